// Round 1
// baseline (200.822 us; speedup 1.0000x reference)
//
#include <hip/hip_runtime.h>
#include <math.h>

// Problem constants (GeoFormer.generate_proposal, ScanNet config)
#define BB 4
#define QQ 128
#define NN 50000
#define CC 20
#define ROWS (BB * QQ)          // 512
#define NV4 (NN / 4)            // 12500 float4 per row
#define BPR 13                  // blocks per row for the N-dim pass
#define THRESH_CNT 50
#define MIN_CLS 4

// Workspace layout (8 KB, re-initialized by k0 every call since harness
// poisons ws with 0xAA before each timed launch)
struct Ws {
    float sum[ROWS];
    int   cnt[ROWS];
    int   cls[ROWS];
    int   valid[ROWS];
};

// K0: per-(b,q) argmax over C=20 class logits (jnp.argmax tie-break = first
// max, i.e. strict '>' while scanning forward), and zero the accumulators.
__global__ void k0_argmax_zero(const float* __restrict__ cls_logits, Ws* ws) {
    int r = blockIdx.x * blockDim.x + threadIdx.x;
    if (r >= ROWS) return;
    const float* p = cls_logits + r * CC;
    float best = p[0];
    int bi = 0;
    #pragma unroll
    for (int c = 1; c < CC; ++c) {
        float v = p[c];
        if (v > best) { best = v; bi = c; }
    }
    ws->cls[r] = bi;
    ws->sum[r] = 0.0f;
    ws->cnt[r] = 0;
}

// K1: main pass. grid = (BPR, ROWS). Writes sel as 0/1 float to out_mask,
// accumulates per-row count and sum-of-sigmoid via block reduce + atomics.
__global__ __launch_bounds__(256) void k1_select(
        const float* __restrict__ mask_logits,
        const int*   __restrict__ seg_pred,
        float* __restrict__ out_mask,
        Ws* __restrict__ ws) {
    const int row = blockIdx.y;          // 0..511  (b*Q + q)
    const int b   = row >> 7;            // row / Q
    const int cls = ws->cls[row];

    const float4* __restrict__ ml = (const float4*)(mask_logits + (size_t)row * NN);
    const int4*   __restrict__ sp = (const int4*)(seg_pred + b * NN);
    float4* __restrict__ om = (float4*)(out_mask + (size_t)row * NN);

    float lsum = 0.0f;
    int   lcnt = 0;

    for (int i = blockIdx.x * blockDim.x + threadIdx.x; i < NV4; i += BPR * 256) {
        float4 v = ml[i];
        int4   s = sp[i];
        float4 o;
        // sigmoid(x) > 0.5  <=>  x > 0
        bool s0 = (v.x > 0.0f) && (s.x == cls);
        bool s1 = (v.y > 0.0f) && (s.y == cls);
        bool s2 = (v.z > 0.0f) && (s.z == cls);
        bool s3 = (v.w > 0.0f) && (s.w == cls);
        o.x = s0 ? 1.0f : 0.0f;
        o.y = s1 ? 1.0f : 0.0f;
        o.z = s2 ? 1.0f : 0.0f;
        o.w = s3 ? 1.0f : 0.0f;
        if (s0) { lsum += 1.0f / (1.0f + __expf(-v.x)); lcnt++; }
        if (s1) { lsum += 1.0f / (1.0f + __expf(-v.y)); lcnt++; }
        if (s2) { lsum += 1.0f / (1.0f + __expf(-v.z)); lcnt++; }
        if (s3) { lsum += 1.0f / (1.0f + __expf(-v.w)); lcnt++; }
        om[i] = o;
    }

    // wave64 shuffle reduce
    #pragma unroll
    for (int off = 32; off > 0; off >>= 1) {
        lsum += __shfl_down(lsum, off);
        lcnt += __shfl_down(lcnt, off);
    }
    __shared__ float ssum[4];
    __shared__ int   scnt[4];
    const int wave = threadIdx.x >> 6;
    const int lane = threadIdx.x & 63;
    if (lane == 0) { ssum[wave] = lsum; scnt[wave] = lcnt; }
    __syncthreads();
    if (threadIdx.x == 0) {
        float ts = ssum[0] + ssum[1] + ssum[2] + ssum[3];
        int   tc = scnt[0] + scnt[1] + scnt[2] + scnt[3];
        atomicAdd(&ws->sum[row], ts);
        atomicAdd(&ws->cnt[row], tc);
    }
}

// K2: finalize per-row outputs (scores, valid, cls_pred) and stash valid flag.
__global__ void k2_finalize(float* __restrict__ out, Ws* __restrict__ ws) {
    int r = blockIdx.x * blockDim.x + threadIdx.x;
    if (r >= ROWS) return;
    int   cnt = ws->cnt[r];
    int   cls = ws->cls[r];
    float sum = ws->sum[r];
    int valid = (cnt >= THRESH_CNT) && (cls >= MIN_CLS);
    ws->valid[r] = valid;
    float* tail = out + (size_t)ROWS * NN;
    tail[r]            = valid ? (sum / (float)max(cnt, 1)) : 0.0f;  // scores
    tail[ROWS + r]     = valid ? 1.0f : 0.0f;                        // valid
    tail[2 * ROWS + r] = (float)cls;                                 // cls_pred
}

// K2b: global_ids = fg_idxs reshaped, int -> float copy (vectorized).
__global__ void k2b_gids(const int* __restrict__ fg, float* __restrict__ out) {
    int i = blockIdx.x * blockDim.x + threadIdx.x;
    const int nv4 = (BB * NN) / 4;   // 50000
    if (i < nv4) {
        int4 v = ((const int4*)fg)[i];
        float4 o;
        o.x = (float)v.x; o.y = (float)v.y; o.z = (float)v.z; o.w = (float)v.w;
        ((float4*)out)[i] = o;
    }
}

// K3: zero the mask rows where !valid (expected ~20% of rows).
__global__ __launch_bounds__(256) void k3_fixup(
        float* __restrict__ out_mask, const Ws* __restrict__ ws) {
    const int row = blockIdx.y;
    if (ws->valid[row]) return;      // wave-uniform early exit
    float4* __restrict__ om = (float4*)(out_mask + (size_t)row * NN);
    const float4 z = {0.0f, 0.0f, 0.0f, 0.0f};
    for (int i = blockIdx.x * blockDim.x + threadIdx.x; i < NV4; i += BPR * 256) {
        om[i] = z;
    }
}

extern "C" void kernel_launch(void* const* d_in, const int* in_sizes, int n_in,
                              void* d_out, int out_size, void* d_ws, size_t ws_size,
                              hipStream_t stream) {
    const float* mask_logits = (const float*)d_in[0];   // [B,Q,N] f32
    const float* cls_logits  = (const float*)d_in[1];   // [B,Q,C] f32
    const int*   seg_pred    = (const int*)d_in[2];     // [B,N]   int
    const int*   fg_idxs     = (const int*)d_in[3];     // [B*N]   int

    float* out = (float*)d_out;
    Ws* ws = (Ws*)d_ws;

    // Output layout (flat, return order):
    //   [0, ROWS*NN)                       proposal_masks
    //   [ROWS*NN, +ROWS)                   scores
    //   [.., +ROWS)                        valid
    //   [.., +ROWS)                        cls_pred
    //   [.., +BB*NN)                       global_ids
    float* out_mask = out;
    float* out_gids = out + (size_t)ROWS * NN + 3 * ROWS;

    k0_argmax_zero<<<(ROWS + 255) / 256, 256, 0, stream>>>(cls_logits, ws);

    dim3 g1(BPR, ROWS);
    k1_select<<<g1, 256, 0, stream>>>(mask_logits, seg_pred, out_mask, ws);

    k2_finalize<<<(ROWS + 255) / 256, 256, 0, stream>>>(out, ws);

    k2b_gids<<<((BB * NN) / 4 + 255) / 256, 256, 0, stream>>>(fg_idxs, out_gids);

    k3_fixup<<<g1, 256, 0, stream>>>(out_mask, ws);
}

// Round 3
// 195.596 us; speedup vs baseline: 1.0267x; 1.0267x over previous
//
#include <hip/hip_runtime.h>
#include <math.h>

// Problem constants (GeoFormer.generate_proposal, ScanNet config)
#define BB 4
#define QQ 128
#define NN 50000
#define CC 20
#define ROWS (BB * QQ)          // 512
#define NV4 (NN / 4)            // 12500 float4 per row
#define TPB 256
#define UNROLL 4
#define BPR 13                  // ceil(12500 / (256*4)) = 13 blocks per row
#define THRESH_CNT 50
#define MIN_CLS 4

// Native clang vector types — required for __builtin_nontemporal_store
typedef float f32x4 __attribute__((ext_vector_type(4)));
typedef int   i32x4 __attribute__((ext_vector_type(4)));

// Workspace (re-initialized by k0 every call; harness poisons ws with 0xAA)
struct Ws {
    float sum[ROWS];
    int   cnt[ROWS];
    int   cls[ROWS];
    int   valid[ROWS];
};

// K0: per-(b,q) argmax over C=20 class logits (jnp.argmax tie-break = first
// max, i.e. strict '>' forward scan), and zero the accumulators.
__global__ void k0_argmax_zero(const float* __restrict__ cls_logits, Ws* ws) {
    int r = blockIdx.x * blockDim.x + threadIdx.x;
    if (r >= ROWS) return;
    const float* p = cls_logits + r * CC;
    float best = p[0];
    int bi = 0;
    #pragma unroll
    for (int c = 1; c < CC; ++c) {
        float v = p[c];
        if (v > best) { best = v; bi = c; }
    }
    ws->cls[r] = bi;
    ws->sum[r] = 0.0f;
    ws->cnt[r] = 0;
}

// K1: main pass. grid = (BPR, ROWS). One tile of UNROLL f32x4 per thread:
// batch all loads first (8 in flight), branchless compute, NT stores.
__global__ __launch_bounds__(256) void k1_select(
        const float* __restrict__ mask_logits,
        const int*   __restrict__ seg_pred,
        float* __restrict__ out_mask,
        Ws* __restrict__ ws) {
    const int row = blockIdx.y;          // 0..511  (b*Q + q)
    const int b   = row >> 7;            // row / Q
    const int cls = ws->cls[row];

    const f32x4* __restrict__ ml = (const f32x4*)(mask_logits + (size_t)row * NN);
    const i32x4* __restrict__ sp = (const i32x4*)(seg_pred + b * NN);
    f32x4* __restrict__ om = (f32x4*)(out_mask + (size_t)row * NN);

    const int idx0 = blockIdx.x * (TPB * UNROLL) + threadIdx.x;

    f32x4 v[UNROLL];
    i32x4 s[UNROLL];
    bool  act[UNROLL];
    #pragma unroll
    for (int j = 0; j < UNROLL; ++j) {
        int idx = idx0 + j * TPB;
        act[j] = (idx < NV4);
        if (act[j]) {
            v[j] = ml[idx];
            s[j] = sp[idx];
        }
    }

    float lsum = 0.0f;
    int   lcnt = 0;
    #pragma unroll
    for (int j = 0; j < UNROLL; ++j) {
        if (!act[j]) continue;
        int idx = idx0 + j * TPB;
        f32x4 vv = v[j];
        i32x4 ss = s[j];
        // sigmoid(x) > 0.5  <=>  x > 0 ; branchless select + accumulate
        bool s0 = (vv.x > 0.0f) & (ss.x == cls);
        bool s1 = (vv.y > 0.0f) & (ss.y == cls);
        bool s2 = (vv.z > 0.0f) & (ss.z == cls);
        bool s3 = (vv.w > 0.0f) & (ss.w == cls);
        float g0 = 1.0f / (1.0f + __expf(-vv.x));
        float g1 = 1.0f / (1.0f + __expf(-vv.y));
        float g2 = 1.0f / (1.0f + __expf(-vv.z));
        float g3 = 1.0f / (1.0f + __expf(-vv.w));
        f32x4 o;
        o.x = s0 ? 1.0f : 0.0f;
        o.y = s1 ? 1.0f : 0.0f;
        o.z = s2 ? 1.0f : 0.0f;
        o.w = s3 ? 1.0f : 0.0f;
        lsum += (s0 ? g0 : 0.0f) + (s1 ? g1 : 0.0f)
              + (s2 ? g2 : 0.0f) + (s3 ? g3 : 0.0f);
        lcnt += (int)s0 + (int)s1 + (int)s2 + (int)s3;
        __builtin_nontemporal_store(o, &om[idx]);
    }

    // wave64 shuffle reduce
    #pragma unroll
    for (int off = 32; off > 0; off >>= 1) {
        lsum += __shfl_down(lsum, off);
        lcnt += __shfl_down(lcnt, off);
    }
    __shared__ float ssum[4];
    __shared__ int   scnt[4];
    const int wave = threadIdx.x >> 6;
    const int lane = threadIdx.x & 63;
    if (lane == 0) { ssum[wave] = lsum; scnt[wave] = lcnt; }
    __syncthreads();
    if (threadIdx.x == 0) {
        float ts = ssum[0] + ssum[1] + ssum[2] + ssum[3];
        int   tc = scnt[0] + scnt[1] + scnt[2] + scnt[3];
        atomicAdd(&ws->sum[row], ts);
        atomicAdd(&ws->cnt[row], tc);
    }
}

// K2: finalize per-row outputs (scores, valid, cls_pred) + global_ids copy.
__global__ void k2_finalize_gids(const int* __restrict__ fg,
                                 float* __restrict__ out,
                                 Ws* __restrict__ ws) {
    const int idx = blockIdx.x * blockDim.x + threadIdx.x;
    if (idx < ROWS) {
        int   cnt = ws->cnt[idx];
        int   cls = ws->cls[idx];
        float sum = ws->sum[idx];
        int valid = (cnt >= THRESH_CNT) && (cls >= MIN_CLS);
        ws->valid[idx] = valid;
        float* tail = out + (size_t)ROWS * NN;
        tail[idx]            = valid ? (sum / (float)max(cnt, 1)) : 0.0f;  // scores
        tail[ROWS + idx]     = valid ? 1.0f : 0.0f;                        // valid
        tail[2 * ROWS + idx] = (float)cls;                                 // cls_pred
    }
    const int nv4 = (BB * NN) / 4;   // 50000
    if (idx < nv4) {
        float* gids = out + (size_t)ROWS * NN + 3 * ROWS;
        i32x4 v = ((const i32x4*)fg)[idx];
        f32x4 o;
        o.x = (float)v.x; o.y = (float)v.y; o.z = (float)v.z; o.w = (float)v.w;
        __builtin_nontemporal_store(o, &((f32x4*)gids)[idx]);
    }
}

// K3: zero the mask rows where !valid (expected ~20% of rows).
__global__ __launch_bounds__(256) void k3_fixup(
        float* __restrict__ out_mask, const Ws* __restrict__ ws) {
    const int row = blockIdx.y;
    if (ws->valid[row]) return;      // wave-uniform early exit
    f32x4* __restrict__ om = (f32x4*)(out_mask + (size_t)row * NN);
    const f32x4 z = {0.0f, 0.0f, 0.0f, 0.0f};
    const int idx0 = blockIdx.x * (TPB * UNROLL) + threadIdx.x;
    #pragma unroll
    for (int j = 0; j < UNROLL; ++j) {
        int idx = idx0 + j * TPB;
        if (idx < NV4) __builtin_nontemporal_store(z, &om[idx]);
    }
}

extern "C" void kernel_launch(void* const* d_in, const int* in_sizes, int n_in,
                              void* d_out, int out_size, void* d_ws, size_t ws_size,
                              hipStream_t stream) {
    const float* mask_logits = (const float*)d_in[0];   // [B,Q,N] f32
    const float* cls_logits  = (const float*)d_in[1];   // [B,Q,C] f32
    const int*   seg_pred    = (const int*)d_in[2];     // [B,N]   int
    const int*   fg_idxs     = (const int*)d_in[3];     // [B*N]   int

    float* out = (float*)d_out;
    Ws* ws = (Ws*)d_ws;

    // Output layout (flat, return order):
    //   [0, ROWS*NN)     proposal_masks
    //   [+ROWS)          scores
    //   [+ROWS)          valid
    //   [+ROWS)          cls_pred
    //   [+BB*NN)         global_ids
    float* out_mask = out;

    k0_argmax_zero<<<(ROWS + 255) / 256, 256, 0, stream>>>(cls_logits, ws);

    dim3 g1(BPR, ROWS);
    k1_select<<<g1, TPB, 0, stream>>>(mask_logits, seg_pred, out_mask, ws);

    const int gids_blocks = ((BB * NN) / 4 + 255) / 256;   // 196, covers ROWS too
    k2_finalize_gids<<<gids_blocks, 256, 0, stream>>>(fg_idxs, out, ws);

    k3_fixup<<<g1, TPB, 0, stream>>>(out_mask, ws);
}